// Round 9
// baseline (214.587 us; speedup 1.0000x reference)
//
#include <hip/hip_runtime.h>

// Biaffine: B=8, L=512, H=768, O=12
// inputs (B,L,H) fp32 ; weight1 (H,O,H) fp32 ; weight2 (2H+1,O) fp32 ;
// mask (B,L) int32 ; out (B,O,L,L) FLOAT32.
//
// R17: operand-swapped epilogues. R16 (204us, absmax 12.25) left both GEMM
// epilogues issuing 128 SCALAR stores/thread (MFMA C-layout: col=lane&15 is
// the output fast axis). Swap A<->B in both GEMMs (cores are symmetric) so
// each lane holds 4 CONSECUTIVE fast-axis outputs per reg group: gemm2 ->
// 32 float4 stores/thread (4-lane col groups = 64B segments), gemm1 -> 32
// dword stores (4 packed fp8). 4x fewer VMEM store instrs on the 100MB out
// stream. Math order per element unchanged -> absmax identical.
// gemm1 = fp4xfp4 sync-dbuf (A-op=W4, B-op=A4); gemm2 = fp8xfp8 counted
// depth-2 (A-op=A8, B-op=U8). prep unchanged from R16.

#define NEGV 1e12f

typedef __attribute__((ext_vector_type(4))) float f32x4;
typedef __attribute__((ext_vector_type(8))) int   i32x8;

// ---- float -> OCP e4m3fn (software fallback: flush |v|<2^-6, RHU, sat 448) ----
__device__ __forceinline__ unsigned char f2fp8(float f) {
    union { float f; unsigned u; } c; c.f = f;
    unsigned s = (c.u >> 24) & 0x80;
    unsigned a = c.u & 0x7FFFFFFF;
    if (a < 0x3C800000u) return (unsigned char)s;        // |v| < 2^-6 -> 0
    a += 0x80000;                                        // round at bit 20
    int e = (int)(a >> 23) - 127;
    unsigned m = (a >> 20) & 7;
    if (e > 8 || (e == 8 && m == 7)) return (unsigned char)(s | 0x7E);  // sat 448
    return (unsigned char)(s | ((e + 7) << 3) | m);
}

// two floats -> two packed e4m3 bytes (HW cvt if available: RNE + denormals)
__device__ __forceinline__ unsigned pk_fp8x2(float a, float b) {
#if __has_builtin(__builtin_amdgcn_cvt_pk_fp8_f32)
    return (unsigned)__builtin_amdgcn_cvt_pk_fp8_f32(a, b, 0, false) & 0xFFFFu;
#else
    return (unsigned)f2fp8(a) | ((unsigned)f2fp8(b) << 8);
#endif
}

// e4m3fn byte -> float (HW cvt if available)
__device__ __forceinline__ float fp8_to_f32(unsigned char b) {
#if __has_builtin(__builtin_amdgcn_cvt_f32_fp8)
    return __builtin_amdgcn_cvt_f32_fp8((int)b, 0);
#else
    const int s = b >> 7, e = (b >> 3) & 15, m = b & 7;
    float mag = e ? __builtin_ldexpf((float)(8 + m), e - 10)
                  : __builtin_ldexpf((float)m, -9);
    return s ? -mag : mag;
#endif
}

// ---- float -> MX fp4 (e2m1) code, round-to-nearest; grid {0,.5,1,1.5,2,3,4,6} ----
__device__ __forceinline__ unsigned f2fp4(float f) {
    const float a = fabsf(f);
    const unsigned s = (__float_as_uint(f) >> 28) & 8u;
    unsigned c;
    if      (a < 0.25f) c = 0;
    else if (a < 0.75f) c = 1;
    else if (a < 1.25f) c = 2;
    else if (a < 1.75f) c = 3;
    else if (a < 2.5f)  c = 4;
    else if (a < 3.5f)  c = 5;
    else if (a < 5.0f)  c = 6;
    else                c = 7;
    return s | c;
}

// global->LDS async copy, 16B per lane; LDS dest is wave-uniform base + lane*16
#define GLDS(gp, lp) __builtin_amdgcn_global_load_lds( \
    (__attribute__((address_space(1))) void*)(gp),     \
    (__attribute__((address_space(3))) void*)(lp), 16, 0, 0)

// ------- fused prep: cast A -> fp4+fp8 | transpose W1 -> fp4 x128 | W ext rows -------
// blocks [0,1536): cast inputs, 8 floats -> 1 dword A4 nibbles + 2 dwords A8.
// blocks [1536,3264): 64x64 transpose tiles of weight1 (768x9216) -> W4 rows.
// blocks [3264,3520): W4 ext rows 9216..9471 (wa^T*128, wb^T*128, zeros).
__global__ __launch_bounds__(256) void prep_kernel(
    const float* __restrict__ in, const float* __restrict__ w1,
    const float* __restrict__ w2, unsigned* __restrict__ A4,
    unsigned* __restrict__ A8, unsigned char* __restrict__ W4) {
    __shared__ float t[64][68];
    const int bx  = blockIdx.x;
    const int tid = threadIdx.x;
    if (bx < 1536) {                       // ---- cast inputs -> fp4 (x2) + fp8 ----
        const int i = bx * 256 + tid;      // < 393216
        const float4 v0 = ((const float4*)in)[2 * i];
        const float4 v1 = ((const float4*)in)[2 * i + 1];
        A4[i] = f2fp4(v0.x * 2.0f)        | (f2fp4(v0.y * 2.0f) << 4)
              | (f2fp4(v0.z * 2.0f) << 8) | (f2fp4(v0.w * 2.0f) << 12)
              | (f2fp4(v1.x * 2.0f) << 16)| (f2fp4(v1.y * 2.0f) << 20)
              | (f2fp4(v1.z * 2.0f) << 24)| (f2fp4(v1.w * 2.0f) << 28);
        A8[2 * i]     = pk_fp8x2(v0.x, v0.y) | (pk_fp8x2(v0.z, v0.w) << 16);
        A8[2 * i + 1] = pk_fp8x2(v1.x, v1.y) | (pk_fp8x2(v1.z, v1.w) << 16);
    } else if (bx < 3264) {                // ---- transpose weight1 -> fp4 (x128) ----
        const int b2 = bx - 1536;          // 0..1727
        const int n0 = (b2 % 144) * 64;    // 9216/64 = 144
        const int i0 = (b2 / 144) * 64;    // 768/64  = 12
        const int g  = tid >> 4;           // 0..15
        const int q  = tid & 15;           // 0..15
        #pragma unroll
        for (int p = 0; p < 4; ++p) {      // load 16 rows x 64 cols per phase
            const int il = p * 16 + g;
            float4 v = *(const float4*)(w1 + (size_t)(i0 + il) * 9216 + n0 + q * 4);
            *(float4*)&t[il][q * 4] = v;
        }
        __syncthreads();
        #pragma unroll
        for (int p = 0; p < 2; ++p) {      // 32 out-rows x 8 dword-writers per pass
            const int nl = p * 32 + (tid >> 3);
            const int iq = (tid & 7) * 8;
            unsigned w = 0;
            #pragma unroll
            for (int e = 0; e < 8; ++e)
                w |= f2fp4(t[iq + e][nl] * 128.0f) << (4 * e);
            *(unsigned*)(W4 + (size_t)(n0 + nl) * 384 + (i0 >> 1) + (tid & 7) * 4) = w;
        }
    } else {                               // ---- extension rows 9216..9471 ----
        const int j = bx - 3264;           // 0..255 -> W4 row 9216+j
        unsigned char* dst = W4 + (size_t)(9216 + j) * 384;
        if (j < 24) {                      // wa (j<12) / wb (j>=12) column, x128
            if (tid < 128) {
                const int h0 = tid * 6;
                #pragma unroll
                for (int k = 0; k < 3; ++k) {
                    const int h = h0 + 2 * k;
                    const int c0 = (j < 12) ? (h * 12 + j)       : ((768 + h) * 12 + (j - 12));
                    const int c1 = (j < 12) ? ((h + 1) * 12 + j) : ((769 + h) * 12 + (j - 12));
                    dst[(h >> 1)] = (unsigned char)(f2fp4(w2[c0] * 128.0f)
                                                  | (f2fp4(w2[c1] * 128.0f) << 4));
                }
            }
        } else {                           // zero pad rows
            if (tid < 96) ((unsigned*)dst)[tid] = 0u;
        }
    }
}

// -------- 256x256 fp4 bt-GEMM core (K=768 = 3 tiles of 256 elems = 128 B) --------
// depth-1 dbuf + __syncthreads. acc[mi][ni]: rows = A-operand dim, cols = B dim.
__device__ __forceinline__ void gemm256_fp4(
    const unsigned char* __restrict__ A, int lda,
    const unsigned char* __restrict__ B, int ldb,
    char* As, char* Bs, f32x4 (&acc)[8][4], int sA, int sB) {
    const int tid  = threadIdx.x;
    const int lane = tid & 63;
    const int wave = tid >> 6;
    const unsigned char* aSrc[4]; const unsigned char* bSrc[4];
    int off[4];
    #pragma unroll
    for (int p = 0; p < 4; ++p) {
        const int cc = tid + 512 * p;
        const int row = cc >> 3, slot = cc & 7;
        const int g = slot ^ (row & 7);                 // global chunk staged here
        aSrc[p] = A + (size_t)row * lda + g * 16;
        bSrc[p] = B + (size_t)row * ldb + g * 16;
        off[p] = cc * 16;
    }
    const int wm = (wave >> 2) * 128;
    const int wn = (wave & 3) * 64;
    const int fr = lane & 15;
    const int kg = lane >> 4;

#define READ_FRAG4(dst, buf, rr, kk) do {                                         \
        const uint4 q_ = *(const uint4*)((buf) + (rr) * 128 +                     \
                                         (((kk) * 4 + kg) ^ ((rr) & 7)) * 16);    \
        dst[0] = q_.x; dst[1] = q_.y; dst[2] = q_.z; dst[3] = q_.w;               \
        dst[4] = 0; dst[5] = 0; dst[6] = 0; dst[7] = 0;                           \
    } while (0)

    #pragma unroll
    for (int p = 0; p < 4; ++p) GLDS(aSrc[p], As + off[p]);
    #pragma unroll
    for (int p = 0; p < 4; ++p) GLDS(bSrc[p], Bs + off[p]);
    __syncthreads();
    int cur = 0;
    #pragma unroll
    for (int t = 1; t <= 3; ++t) {
        const int nxt = cur ^ 1;
        if (t < 3) {                     // issue next-tile prefetch FIRST
            const int kk = t * 128;
            #pragma unroll
            for (int p = 0; p < 4; ++p) GLDS(aSrc[p] + kk, As + nxt * 32768 + off[p]);
            #pragma unroll
            for (int p = 0; p < 4; ++p) GLDS(bSrc[p] + kk, Bs + nxt * 32768 + off[p]);
        }
        const char* Ab = As + cur * 32768;
        const char* Bb = Bs + cur * 32768;
        #pragma unroll
        for (int kk = 0; kk < 2; ++kk) {
            i32x8 bf[4];
            #pragma unroll
            for (int ni = 0; ni < 4; ++ni) READ_FRAG4(bf[ni], Bb, wn + ni * 16 + fr, kk);
            #pragma unroll
            for (int mi = 0; mi < 8; ++mi) {
                i32x8 af; READ_FRAG4(af, Ab, wm + mi * 16 + fr, kk);
                #pragma unroll
                for (int ni = 0; ni < 4; ++ni)
                    acc[mi][ni] = __builtin_amdgcn_mfma_scale_f32_16x16x128_f8f6f4(
                        af, bf[ni], acc[mi][ni], 4, 4, 0, sA, 0, sB);
            }
        }
        __syncthreads();                 // drains prefetch + fences LDS
        cur = nxt;
    }
#undef READ_FRAG4
}

// -------- 256x256xBK=128 fp8 bt-GEMM core, depth-2 counted-vmcnt --------
__device__ __forceinline__ void gemm256_fp8(
    const unsigned char* __restrict__ A, int lda,
    const unsigned char* __restrict__ B, int ldb,
    char* As, char* Bs, f32x4 (&acc)[8][4], int sA, int sB) {
    const int tid  = threadIdx.x;
    const int lane = tid & 63;
    const int wave = tid >> 6;
    const unsigned char* aSrc[4]; const unsigned char* bSrc[4];
    int off[4];
    #pragma unroll
    for (int p = 0; p < 4; ++p) {
        const int cc = tid + 512 * p;
        const int row = cc >> 3, slot = cc & 7;
        const int g = slot ^ (row & 7);
        aSrc[p] = A + (size_t)row * lda + g * 16;
        bSrc[p] = B + (size_t)row * ldb + g * 16;
        off[p] = cc * 16;
    }
    const int wm = (wave >> 2) * 128;
    const int wn = (wave & 3) * 64;
    const int fr = lane & 15;
    const int kg = lane >> 4;

    #pragma unroll
    for (int p = 0; p < 4; ++p) GLDS(aSrc[p], As + off[p]);
    #pragma unroll
    for (int p = 0; p < 4; ++p) GLDS(bSrc[p], Bs + off[p]);
    #pragma unroll
    for (int p = 0; p < 4; ++p) GLDS(aSrc[p] + 128, As + 32768 + off[p]);
    #pragma unroll
    for (int p = 0; p < 4; ++p) GLDS(bSrc[p] + 128, Bs + 32768 + off[p]);

    #pragma unroll
    for (int t = 0; t < 6; ++t) {
        const int cur = t & 1;
        if (t < 5) asm volatile("s_waitcnt vmcnt(8)" ::: "memory");
        else       asm volatile("s_waitcnt vmcnt(0)" ::: "memory");
        __builtin_amdgcn_sched_barrier(0);
        __builtin_amdgcn_s_barrier();     // all waves' tile-t data now in LDS
        const char* Ab = As + cur * 32768;
        const char* Bb = Bs + cur * 32768;
        i32x8 bf[4];
        #pragma unroll
        for (int ni = 0; ni < 4; ++ni) {
            const int r = wn + ni * 16 + fr;
            const uint4 lo = *(const uint4*)(Bb + r * 128 + ((2 * kg    ) ^ (r & 7)) * 16);
            const uint4 hi = *(const uint4*)(Bb + r * 128 + ((2 * kg + 1) ^ (r & 7)) * 16);
            bf[ni][0] = lo.x; bf[ni][1] = lo.y; bf[ni][2] = lo.z; bf[ni][3] = lo.w;
            bf[ni][4] = hi.x; bf[ni][5] = hi.y; bf[ni][6] = hi.z; bf[ni][7] = hi.w;
        }
        __builtin_amdgcn_s_setprio(1);
        #pragma unroll
        for (int mi = 0; mi < 8; ++mi) {
            const int r = wm + mi * 16 + fr;
            const uint4 lo = *(const uint4*)(Ab + r * 128 + ((2 * kg    ) ^ (r & 7)) * 16);
            const uint4 hi = *(const uint4*)(Ab + r * 128 + ((2 * kg + 1) ^ (r & 7)) * 16);
            i32x8 af;
            af[0] = lo.x; af[1] = lo.y; af[2] = lo.z; af[3] = lo.w;
            af[4] = hi.x; af[5] = hi.y; af[6] = hi.z; af[7] = hi.w;
            #pragma unroll
            for (int ni = 0; ni < 4; ++ni)
                acc[mi][ni] = __builtin_amdgcn_mfma_scale_f32_16x16x128_f8f6f4(
                    af, bf[ni], acc[mi][ni], 0, 0, 0, sA, 0, sB);
        }
        __builtin_amdgcn_s_setprio(0);
        asm volatile("s_waitcnt lgkmcnt(0)" ::: "memory");
        __builtin_amdgcn_sched_barrier(0);
        __builtin_amdgcn_s_barrier();     // everyone done reading buf[cur]
        if (t < 4) {                      // stage tile t+2 into the freed buffer
            const int kk = (t + 2) * 128;
            #pragma unroll
            for (int p = 0; p < 4; ++p) GLDS(aSrc[p] + kk, As + cur * 32768 + off[p]);
            #pragma unroll
            for (int p = 0; p < 4; ++p) GLDS(bSrc[p] + kk, Bs + cur * 32768 + off[p]);
        }
    }
}

// ---- GEMM1 (operand-swapped): A-op = W4 rows n, B-op = A4 rows m ----
// acc rows = n (U cols), cols = m -> per lane 4 consecutive n per reg group:
// pack 4 fp8 bytes -> one dword store into U8[m][n_base]. 37x16 tiles.
__global__ __launch_bounds__(512, 2) void gemm1_kernel(
    const unsigned char* __restrict__ A4,
    const unsigned char* __restrict__ W4,
    unsigned char* __restrict__ U8) {
    __shared__ __align__(16) char As[2 * 32768];
    __shared__ __align__(16) char Bs[2 * 32768];
    const int orig = blockIdx.x;
    const int swz  = (orig & 7) * 74 + (orig >> 3);   // 592 = 8*74, bijective
    const int m0 = (swz & 15) * 256;
    const int n0 = (swz >> 4) * 256;
    f32x4 acc[8][4] = {};
    // A-op = W4 (w*128 -> 2^-7 = 0x78); B-op = A4 (x*2 -> 2^-1 = 0x7E)
    gemm256_fp4(W4 + (size_t)n0 * 384, 384, A4 + (size_t)m0 * 384, 384,
                As, Bs, acc, 0x78787878, 0x7E7E7E7E);
    const int lane = threadIdx.x & 63;
    const int wave = threadIdx.x >> 6;
    const int wm = (wave >> 2) * 128, wn = (wave & 3) * 64;
    const int rl = (lane >> 4) * 4, cl = lane & 15;
    #pragma unroll
    for (int mi = 0; mi < 8; ++mi) {
        const int nb = n0 + wm + mi * 16 + rl;        // 4 consecutive U cols
        #pragma unroll
        for (int ni = 0; ni < 4; ++ni) {
            const int m = m0 + wn + ni * 16 + cl;     // U row
            const unsigned w = pk_fp8x2(acc[mi][ni][0], acc[mi][ni][1])
                             | (pk_fp8x2(acc[mi][ni][2], acc[mi][ni][3]) << 16);
            *(unsigned*)(U8 + (size_t)m * 9472 + nb) = w;
        }
    }
}

// ---- GEMM2 (operand-swapped) + epilogue: out[b,o,x,y] fp32 ----
// A-op = A8 rows y, B-op = U8 rows x. acc rows = y, cols = x -> per lane 4
// consecutive y per reg group: one float4 store at out[x*512 + y_base].
// li (x) from U8 ext col 9216+o; lj (y) from 9228+o.
__global__ __launch_bounds__(512, 2) void gemm2_kernel(
    const unsigned char* __restrict__ U8,
    const unsigned char* __restrict__ A8,
    const float* __restrict__ w2,
    const int* __restrict__ mask,
    float* __restrict__ out) {
    __shared__ __align__(16) char As[2 * 32768];
    __shared__ __align__(16) char Bs[2 * 32768];
    const int orig = blockIdx.x;
    const int swz  = (orig & 7) * 48 + (orig >> 3);   // 384 = 8*48, bijective
    const int bo = swz >> 2;              // 0..95
    const int b = bo / 12, o = bo % 12;
    const int x0 = (swz & 1) * 256;
    const int y0 = ((swz >> 1) & 1) * 256;
    f32x4 acc[8][4] = {};
    gemm256_fp8(A8 + (size_t)(b * 512 + y0) * 768, 768,
                U8 + (size_t)(b * 512 + x0) * 9472 + (size_t)o * 768, 9472,
                As, Bs, acc, 0x7F7F7F7F, 0x7F7F7F7F);
    const float bias = w2[1536 * 12 + o];
    float* outp = out + (size_t)bo * 512 * 512;
    const int lane = threadIdx.x & 63;
    const int wave = threadIdx.x >> 6;
    const int wm = (wave >> 2) * 128, wn = (wave & 3) * 64;
    const int rl = (lane >> 4) * 4, cl = lane & 15;
    float lix[4]; int mx[4];
    #pragma unroll
    for (int ni = 0; ni < 4; ++ni) {               // per-lane x (output row idx)
        const int x = x0 + wn + ni * 16 + cl;
        lix[ni] = fp8_to_f32(U8[(size_t)(b * 512 + x) * 9472 + 9216 + o]);
        mx[ni]  = mask[b * 512 + x];
    }
    #pragma unroll
    for (int mi = 0; mi < 8; ++mi) {
        const int yb = y0 + wm + mi * 16 + rl;     // 4 consecutive y
        float ljv[4]; int my[4];
        #pragma unroll
        for (int r = 0; r < 4; ++r) {
            ljv[r] = fp8_to_f32(U8[(size_t)(b * 512 + yb + r) * 9472 + 9228 + o]);
            my[r]  = mask[b * 512 + yb + r];
        }
        #pragma unroll
        for (int ni = 0; ni < 4; ++ni) {
            const int x = x0 + wn + ni * 16 + cl;
            float4 v4;
            #pragma unroll
            for (int r = 0; r < 4; ++r) {
                float v = acc[mi][ni][r] + lix[ni] + ljv[r] + bias;
                if (!(mx[ni] & my[r])) v = -NEGV;  // row or col masked -> exactly -1e12
                if (x > yb + r)        v -= NEGV;  // strict lower triangle -> extra -1e12
                ((float*)&v4)[r] = v;
            }
            *(float4*)(outp + (size_t)x * 512 + yb) = v4;
        }
    }
}

extern "C" void kernel_launch(void* const* d_in, const int* in_sizes, int n_in,
                              void* d_out, int out_size, void* d_ws, size_t ws_size,
                              hipStream_t stream) {
    const float* inputs = (const float*)d_in[0];
    const float* w1     = (const float*)d_in[1];
    const float* w2     = (const float*)d_in[2];
    const int*   mask   = (const int*)d_in[3];
    float* outp = (float*)d_out;

    // workspace layout (47.2 MB used)
    char* ws = (char*)d_ws;
    unsigned char* A4 = (unsigned char*)(ws + 0);          //  1,572,864 B (4096 x 384)
    unsigned char* A8 = (unsigned char*)(ws + 1572864);    //  3,145,728 B (4096 x 768)
    unsigned char* W4 = (unsigned char*)(ws + 4718592);    //  3,637,248 B (9472 x 384)
    unsigned char* U8 = (unsigned char*)(ws + 8355840);    // 38,797,312 B (4096 x 9472)

    prep_kernel<<<3520, 256, 0, stream>>>(inputs, w1, w2, (unsigned*)A4,
                                          (unsigned*)A8, W4);
    gemm1_kernel<<<592, 512, 0, stream>>>(A4, W4, U8);
    gemm2_kernel<<<384, 512, 0, stream>>>(U8, A8, w2, mask, outp);
}